// Round 6
// baseline (1089.613 us; speedup 1.0000x reference)
//
#include <hip/hip_runtime.h>

// GPUHungarianMatcher — exact replication of the reference's degenerate "_lsa"
// (minv reset every inner iteration => chain-Dijkstra). One block (4 waves)
// per batch. R6 = R5 with the per-step s_barrier replaced by stamped LDS
// mailboxes + busy-poll (no barrier in the step loop), and the within-lane
// serial min chain replaced by a tree.
//
// Exactness invariants (validated by R2-R5 passing with absmax 0):
//  * cost fp32: fabsf(qx-tX)+fabsf(qy-tY)+np_, reduced fp64: ((double)cf-u)-v
//  * scans read only PRE-search u/v (path rows/cols distinct) => defer updates
//  * argmin: strict <, ascending j => np.argmin first-occurrence tie-break
//    (tree keeps left=smaller k on ties; winner canonicalized with +0.0)
//  * softmax bitwise-identical to the R2 tree (same thread mapping)
//
// Mailbox safety: A={khi:32|idx:12|g:20}, B={klo:32|g:20}; g is a global step
// counter (never reused; total steps << 2^20). 8-byte atomic LDS ops => no
// tearing; per-word stamp => cross-word consistency. Parity-2 slot reuse at
// step s+2 is ordered after every wave's step-s poll (a wave reaches s+2's
// write only after reading all s+1 partials, which require all s polls done).

constexpr int B = 8;
constexpr int Q = 2048;        // columns (queries)
constexpr int T = 256;         // rows (targets)
constexpr int NT = 256;        // threads per block (4 waves)
constexpr int KPT = Q / NT;    // 8 columns per thread, j = 1 + tid + k*256
constexpr int NW = NT / 64;
constexpr double DINF = 1e300;

struct __align__(16) CD { double u; float tx, ty; };   // one ds_read_b128

__device__ __forceinline__ unsigned wave_min_u32_dpp(unsigned a) {
  // full-wave u32 min: row_shr 1,2,4,8 then row_bcast15, row_bcast31;
  // invalid source lanes keep old (bound_ctrl=false, masks 0xf) = identity.
  int v = (int)a, t;
  t = __builtin_amdgcn_update_dpp(v, v, 0x111, 0xf, 0xf, false);
  v = ((unsigned)t < (unsigned)v) ? t : v;
  t = __builtin_amdgcn_update_dpp(v, v, 0x112, 0xf, 0xf, false);
  v = ((unsigned)t < (unsigned)v) ? t : v;
  t = __builtin_amdgcn_update_dpp(v, v, 0x114, 0xf, 0xf, false);
  v = ((unsigned)t < (unsigned)v) ? t : v;
  t = __builtin_amdgcn_update_dpp(v, v, 0x118, 0xf, 0xf, false);
  v = ((unsigned)t < (unsigned)v) ? t : v;
  t = __builtin_amdgcn_update_dpp(v, v, 0x142, 0xf, 0xf, false);
  v = ((unsigned)t < (unsigned)v) ? t : v;
  t = __builtin_amdgcn_update_dpp(v, v, 0x143, 0xf, 0xf, false);
  v = ((unsigned)t < (unsigned)v) ? t : v;
  return (unsigned)__builtin_amdgcn_readlane(v, 63);   // lane 63 = global min
}

__launch_bounds__(NT, 1)
__global__ void hungarian_poll(const float* __restrict__ outs,
                               const float* __restrict__ tgts,
                               int* __restrict__ out) {
  const int b = blockIdx.x;
  const int tid = threadIdx.x;
  const int lane = tid & 63;
  const int wv = tid >> 6;

  __shared__ CD colDat[Q + 1];      // colDat[j] = {u[p[j]], tx[p[j]-1], ty[p[j]-1]}
  __shared__ CD rowDat[T + 1];      // rowDat[r] = {u[r], tx[r-1], ty[r-1]}
  __shared__ short p[Q + 1];        // p[j]: row matched to col j (1-based), 0 free
  __shared__ short visCol[T + 8];   // visit chain: visCol[0]=0
  __shared__ double visD[T + 8];    // delta prefix sums (before step s)
  alignas(8) __shared__ unsigned long long slotA[2][NW];  // {khi|idx|g}
  alignas(8) __shared__ unsigned long long slotB[2][NW];  // {klo|g}
  __shared__ int ansArr[T];
  __shared__ double s_rv[NW];
  __shared__ float sh_f;

  const size_t qbase = (size_t)b * Q;
  const size_t tbase = (size_t)b * T;

  // ---- stage per-thread column data (fixed mapping j = 1 + tid + k*256) ----
  float xs[KPT], qx[KPT], qy[KPT];
#pragma unroll
  for (int k = 0; k < KPT; ++k) {
    const size_t o = (qbase + tid + k * NT) * 3;
    xs[k] = outs[o];
    qx[k] = outs[o + 1];
    qy[k] = outs[o + 2];
  }
  {
    const size_t o = (tbase + tid) * 3;   // T == NT: one target per thread
    rowDat[tid + 1].tx = tgts[o + 1];
    rowDat[tid + 1].ty = tgts[o + 2];
    rowDat[tid + 1].u = 0.0;
    if (tid == 0) { rowDat[0].tx = 0.f; rowDat[0].ty = 0.f; rowDat[0].u = 0.0; }
  }
  if (tid < 2 * NW) {
    ((unsigned long long*)slotA)[tid] = 0ull;   // stamp 0 != any g >= 1
    ((unsigned long long*)slotB)[tid] = 0ull;
  }

  // ---- softmax over Q logits (bitwise-identical to the R2-passing tree) ----
  float lmax = xs[0];
#pragma unroll
  for (int k = 1; k < KPT; ++k) lmax = fmaxf(lmax, xs[k]);
  for (int off = 32; off > 0; off >>= 1) lmax = fmaxf(lmax, __shfl_down(lmax, off));
  if ((tid & 63) == 0) s_rv[tid >> 6] = (double)lmax;
  __syncthreads();
  if (tid == 0) {
    float m2 = (float)s_rv[0];
    for (int w = 1; w < NW; ++w) m2 = fmaxf(m2, (float)s_rv[w]);
    sh_f = m2;
  }
  __syncthreads();
  const float smax = sh_f;
  float ex[KPT];
  float lsum = 0.f;
#pragma unroll
  for (int k = 0; k < KPT; ++k) { ex[k] = expf(xs[k] - smax); lsum += ex[k]; }
  for (int off = 32; off > 0; off >>= 1) lsum += __shfl_down(lsum, off);
  if ((tid & 63) == 0) s_rv[tid >> 6] = (double)lsum;
  __syncthreads();
  if (tid == 0) {
    float s2 = 0.f;
    for (int w = 0; w < NW; ++w) s2 += (float)s_rv[w];
    sh_f = s2;
  }
  __syncthreads();
  const float ssum = sh_f;
  float np_[KPT];
#pragma unroll
  for (int k = 0; k < KPT; ++k) np_[k] = -(ex[k] / ssum);

  // ---- init state ----
  for (int j = tid; j <= Q; j += NT) p[j] = 0;
  if (tid == 0) visCol[0] = 0;
  double vreg[KPT];   // v[j] for this thread's 8 columns
#pragma unroll
  for (int k = 0; k < KPT; ++k) vreg[k] = 0.0;
  unsigned g = 1;     // global step stamp (all threads agree)
  __syncthreads();

  // ---- main loop over rows ----
  for (int i = 1; i <= T; ++i) {
    if (tid == 0) p[0] = (short)i;
    unsigned usedMask = 0;
    double D = 0.0;
    __syncthreads();            // Bs: prev epilogue writes drained
    double ui0 = rowDat[i].u;
    float tX = rowDat[i].tx, tY = rowDat[i].ty;
    int s = 0, S;

    for (;;) {
      // scan my 8 unused columns: cur = ((double)cf - u[i0]) - v[j]
      double cv[KPT];
#pragma unroll
      for (int k = 0; k < KPT; ++k) {
        const float cf = fabsf(qx[k] - tX) + fabsf(qy[k] - tY) + np_[k];
        double cur = ((double)cf - ui0) - vreg[k];
        if (usedMask & (1u << k)) cur = DINF;   // used => never wins strict <
        cv[k] = cur;
      }
      // within-lane tree min, left (smaller k) wins ties => first-occurrence
      double v0 = cv[0]; int k0 = 0;
      if (cv[1] < v0) { v0 = cv[1]; k0 = 1; }
      double v1 = cv[2]; int k1 = 2;
      if (cv[3] < v1) { v1 = cv[3]; k1 = 3; }
      double v2 = cv[4]; int k2 = 4;
      if (cv[5] < v2) { v2 = cv[5]; k2 = 5; }
      double v3 = cv[6]; int k3 = 6;
      if (cv[7] < v3) { v3 = cv[7]; k3 = 7; }
      if (v1 < v0) { v0 = v1; k0 = k1; }
      if (v3 < v2) { v2 = v3; k2 = k3; }
      double bval = v0; int bk = k0;
      if (v2 < v0) { bval = v2; bk = k2; }
      int bidx = 1 + tid + (bk << 8);

      // monotonic u64 bit-key of the per-lane winner (canonicalize -0 -> +0)
      bval += 0.0;
      const long long bb = __double_as_longlong(bval);
      const unsigned long long key = (unsigned long long)bb ^
          ((bb < 0) ? 0xFFFFFFFFFFFFFFFFull : 0x8000000000000000ull);
      const unsigned khi = (unsigned)(key >> 32);
      const unsigned klo = (unsigned)key;

      // wave argmin: DPP min on hi32, ballot for winner, exact ties slow path
      const unsigned minhi = wave_min_u32_dpp(khi);
      const unsigned long long mask = __ballot(khi == minhi);
      unsigned wklo; int widx;
      if (__popcll(mask) == 1) {
        const int wl = (int)__ffsll(mask) - 1;
        wklo = (unsigned)__builtin_amdgcn_readlane((int)klo, wl);
        widx = __builtin_amdgcn_readlane(bidx, wl);
      } else {
        wklo = 0xffffffffu; widx = 0x7fffffff;
        unsigned long long mm = mask;
        while (mm) {
          const int l = (int)__ffsll(mm) - 1; mm &= mm - 1;
          const unsigned lo2 = (unsigned)__builtin_amdgcn_readlane((int)klo, l);
          const int ix2 = __builtin_amdgcn_readlane(bidx, l);
          if (lo2 < wklo || (lo2 == wklo && ix2 < widx)) { wklo = lo2; widx = ix2; }
        }
      }

      // publish this wave's candidate (stamped mailboxes, no barrier)
      const int par = s & 1;
      const unsigned gs = g & 0xFFFFFu;
      if (lane == 0) {
        const unsigned long long Bwr = ((unsigned long long)wklo << 32) | gs;
        const unsigned long long Awr = ((unsigned long long)minhi << 32) |
            ((unsigned long long)((unsigned)widx & 0xFFFu) << 20) | gs;
        __atomic_store_n(&slotB[par][wv], Bwr, __ATOMIC_RELAXED);
        __atomic_store_n(&slotA[par][wv], Awr, __ATOMIC_RELAXED);
      }
      if (tid == 0) visD[s] = D;   // prefix (deltas of steps < s)

      // busy-poll all 4 mailboxes for stamp == gs (broadcast LDS reads)
      unsigned long long Aw[NW], Bw[NW];
      for (;;) {
        bool all = true;
#pragma unroll
        for (int w = 0; w < NW; ++w) {
          Aw[w] = __atomic_load_n(&slotA[par][w], __ATOMIC_RELAXED);
          Bw[w] = __atomic_load_n(&slotB[par][w], __ATOMIC_RELAXED);
          all = all && ((unsigned)(Aw[w] & 0xFFFFFu) == gs)
                    && ((unsigned)(Bw[w] & 0xFFFFFu) == gs);
        }
        if (all) break;
      }
      ++g;

      // cross-wave lexicographic reduce (identical order to R5)
      unsigned long long bkk = ((Aw[0] >> 32) << 32) | (Bw[0] >> 32);
      int bj = (int)((Aw[0] >> 20) & 0xFFFu);
#pragma unroll
      for (int w = 1; w < NW; ++w) {
        const unsigned long long k2b = ((Aw[w] >> 32) << 32) | (Bw[w] >> 32);
        const int j2 = (int)((Aw[w] >> 20) & 0xFFFu);
        if (k2b < bkk || (k2b == bkk && j2 < bj)) { bkk = k2b; bj = j2; }
      }
      // invert bit-key -> delta (bitwise identical on every thread)
      const long long db = (long long)((bkk & 0x8000000000000000ull)
                                           ? (bkk ^ 0x8000000000000000ull) : ~bkk);
      D += __longlong_as_double(db);
      const int j1 = bj;          // selected column, 1-based
      if (tid == ((j1 - 1) & 255)) usedMask |= 1u << ((j1 - 1) >> 8);
      if (tid == 0) visCol[s + 1] = (short)j1;
      const int pj1 = (int)p[j1];     // parallel LDS reads: p[j1] ...
      const CD cd = colDat[j1];       // ... and its row's data (u, tx, ty)
      ++s;
      if (pj1 == 0) { S = s; break; }
      ui0 = cd.u; tX = cd.tx; tY = cd.ty;
    }

    // ---- epilogue: O(path) deferred updates (S <= 256 provable) ----
    __syncthreads();              // E0: in-search LDS traffic done
    const double Dfin = D;
    // snapshot pre-augment rows into registers
    const int rr0 = (tid < S) ? (int)p[(int)visCol[tid]] : 0;
    __syncthreads();              // E1
    if (tid < S) {
      const int cnew = (int)visCol[tid + 1];
      p[cnew] = (short)rr0;                       // augment
      const double unew = rowDat[rr0].u + (Dfin - visD[tid]);
      rowDat[rr0].u = unew;                       // u[row] += Dfin - visD[s]
      CD cd2; cd2.u = unew; cd2.tx = rowDat[rr0].tx; cd2.ty = rowDat[rr0].ty;
      colDat[cnew] = cd2;                         // refresh column cache
    }
    // v updates for used cols visCol[1..S-1] (owner thread applies)
    for (int sv = 1; sv < S; ++sv) {
      const int qv = (int)visCol[sv] - 1;
      if ((qv & 255) == tid) vreg[qv >> 8] -= (Dfin - visD[sv]);
    }
    // next Bs barrier orders these writes before the next search's reads
  }
  __syncthreads();

  // ---- extract assignment, rank-sort (distinct values), write int32 ----
  for (int j = 1 + tid; j <= Q; j += NT) {
    const int pi = (int)p[j];
    if (pi > 0) ansArr[pi - 1] = j - 1;
  }
  __syncthreads();
  const int a = ansArr[tid];
  int rank = 0;
  for (int t2 = 0; t2 < T; ++t2) rank += (ansArr[t2] < a) ? 1 : 0;
  out[(size_t)b * T + rank] = a;                      // row_ind (sorted query idx)
  out[(size_t)B * T + (size_t)b * T + rank] = tid;    // col_ind (target idx)
}

extern "C" void kernel_launch(void* const* d_in, const int* in_sizes, int n_in,
                              void* d_out, int out_size, void* d_ws, size_t ws_size,
                              hipStream_t stream) {
  const float* outs = (const float*)d_in[0];   // (8, 2048, 3) fp32
  const float* tgts = (const float*)d_in[1];   // (8, 256, 3) fp32
  int* out = (int*)d_out;                      // row_ind (8,256) ++ col_ind (8,256)
  hungarian_poll<<<B, NT, 0, stream>>>(outs, tgts, out);
}

// Round 7
// 975.126 us; speedup vs baseline: 1.1174x; 1.1174x over previous
//
#include <hip/hip_runtime.h>

// GPUHungarianMatcher — exact replication of the reference's degenerate "_lsa"
// (minv reset every inner iteration => chain-Dijkstra). One block (4 waves)
// per batch. R7 = R5 (barrier exchange) + packed uint4 mailbox + free-flag in
// colDat (no p[] read in loop) + prefetch of all 4 candidates' colDat before
// the combine (overlaps 2nd LDS trip with combine arithmetic).
//
// Exactness invariants (validated by R2-R6 passing with absmax 0):
//  * cost fp32: fabsf(qx-tX)+fabsf(qy-tY)+np_, reduced fp64: ((double)cf-u)-v
//  * scans read only PRE-search u/v (path rows/cols distinct) => defer updates
//  * argmin: strict <, ascending j => np.argmin first-occurrence tie-break
//    (tree keeps left=smaller k on ties; winner canonicalized with +0.0)
//  * softmax bitwise-identical to the R2 tree (same thread mapping)
//  * free-flag: colDat[j].tx = -1.0f iff column j unmatched (real tx >= 0)

constexpr int B = 8;
constexpr int Q = 2048;        // columns (queries)
constexpr int T = 256;         // rows (targets)
constexpr int NT = 256;        // threads per block (4 waves)
constexpr int KPT = Q / NT;    // 8 columns per thread, j = 1 + tid + k*256
constexpr int NW = NT / 64;
constexpr double DINF = 1e300;

struct __align__(16) CD { double u; float tx, ty; };   // one ds_read_b128

__device__ __forceinline__ unsigned wave_min_u32_dpp(unsigned a) {
  // full-wave u32 min: row_shr 1,2,4,8 then row_bcast15, row_bcast31;
  // invalid source lanes keep old (bound_ctrl=false, masks 0xf) = identity.
  int v = (int)a, t;
  t = __builtin_amdgcn_update_dpp(v, v, 0x111, 0xf, 0xf, false);
  v = ((unsigned)t < (unsigned)v) ? t : v;
  t = __builtin_amdgcn_update_dpp(v, v, 0x112, 0xf, 0xf, false);
  v = ((unsigned)t < (unsigned)v) ? t : v;
  t = __builtin_amdgcn_update_dpp(v, v, 0x114, 0xf, 0xf, false);
  v = ((unsigned)t < (unsigned)v) ? t : v;
  t = __builtin_amdgcn_update_dpp(v, v, 0x118, 0xf, 0xf, false);
  v = ((unsigned)t < (unsigned)v) ? t : v;
  t = __builtin_amdgcn_update_dpp(v, v, 0x142, 0xf, 0xf, false);
  v = ((unsigned)t < (unsigned)v) ? t : v;
  t = __builtin_amdgcn_update_dpp(v, v, 0x143, 0xf, 0xf, false);
  v = ((unsigned)t < (unsigned)v) ? t : v;
  return (unsigned)__builtin_amdgcn_readlane(v, 63);   // lane 63 = global min
}

__launch_bounds__(NT, 1)
__global__ void hungarian_r7(const float* __restrict__ outs,
                             const float* __restrict__ tgts,
                             int* __restrict__ out) {
  const int b = blockIdx.x;
  const int tid = threadIdx.x;
  const int lane = tid & 63;
  const int wv = tid >> 6;

  __shared__ CD colDat[Q + 1];      // colDat[j] = {u[p[j]], tx[p[j]-1], ty[p[j]-1]}
                                    // tx = -1.0f marks a FREE column
  __shared__ CD rowDat[T + 1];      // rowDat[r] = {u[r], tx[r-1], ty[r-1]}
  __shared__ short p[Q + 1];        // p[j]: row matched to col j (1-based), 0 free
  __shared__ short visCol[T + 8];   // visit chain: visCol[0]=0
  __shared__ double visD[T + 8];    // delta prefix sums (before step s)
  __shared__ uint4 pk[2][NW];       // packed mailbox {khi, klo, idx, 0} (parity)
  __shared__ int ansArr[T];
  __shared__ double s_rv[NW];
  __shared__ float sh_f;

  const size_t qbase = (size_t)b * Q;
  const size_t tbase = (size_t)b * T;

  // ---- stage per-thread column data (fixed mapping j = 1 + tid + k*256) ----
  float xs[KPT], qx[KPT], qy[KPT];
#pragma unroll
  for (int k = 0; k < KPT; ++k) {
    const size_t o = (qbase + tid + k * NT) * 3;
    xs[k] = outs[o];
    qx[k] = outs[o + 1];
    qy[k] = outs[o + 2];
  }
  {
    const size_t o = (tbase + tid) * 3;   // T == NT: one target per thread
    rowDat[tid + 1].tx = tgts[o + 1];
    rowDat[tid + 1].ty = tgts[o + 2];
    rowDat[tid + 1].u = 0.0;
    if (tid == 0) { rowDat[0].tx = 0.f; rowDat[0].ty = 0.f; rowDat[0].u = 0.0; }
  }

  // ---- softmax over Q logits (bitwise-identical to the R2-passing tree) ----
  float lmax = xs[0];
#pragma unroll
  for (int k = 1; k < KPT; ++k) lmax = fmaxf(lmax, xs[k]);
  for (int off = 32; off > 0; off >>= 1) lmax = fmaxf(lmax, __shfl_down(lmax, off));
  if ((tid & 63) == 0) s_rv[tid >> 6] = (double)lmax;
  __syncthreads();
  if (tid == 0) {
    float m2 = (float)s_rv[0];
    for (int w = 1; w < NW; ++w) m2 = fmaxf(m2, (float)s_rv[w]);
    sh_f = m2;
  }
  __syncthreads();
  const float smax = sh_f;
  float ex[KPT];
  float lsum = 0.f;
#pragma unroll
  for (int k = 0; k < KPT; ++k) { ex[k] = expf(xs[k] - smax); lsum += ex[k]; }
  for (int off = 32; off > 0; off >>= 1) lsum += __shfl_down(lsum, off);
  if ((tid & 63) == 0) s_rv[tid >> 6] = (double)lsum;
  __syncthreads();
  if (tid == 0) {
    float s2 = 0.f;
    for (int w = 0; w < NW; ++w) s2 += (float)s_rv[w];
    sh_f = s2;
  }
  __syncthreads();
  const float ssum = sh_f;
  float np_[KPT];
#pragma unroll
  for (int k = 0; k < KPT; ++k) np_[k] = -(ex[k] / ssum);

  // ---- init state ----
  for (int j = tid; j <= Q; j += NT) {
    p[j] = 0;
    CD c0; c0.u = 0.0; c0.tx = -1.0f; c0.ty = 0.0f;   // all columns free
    colDat[j] = c0;
  }
  if (tid == 0) visCol[0] = 0;
  double vreg[KPT];   // v[j] for this thread's 8 columns
#pragma unroll
  for (int k = 0; k < KPT; ++k) vreg[k] = 0.0;
  __syncthreads();

  // ---- main loop over rows ----
  for (int i = 1; i <= T; ++i) {
    if (tid == 0) p[0] = (short)i;
    unsigned usedMask = 0;
    double D = 0.0;
    __syncthreads();            // Bs: prev epilogue writes drained
    double ui0 = rowDat[i].u;
    float tX = rowDat[i].tx, tY = rowDat[i].ty;
    int s = 0, S;

    for (;;) {
      // scan my 8 unused columns: cur = ((double)cf - u[i0]) - v[j]
      double cv[KPT];
#pragma unroll
      for (int k = 0; k < KPT; ++k) {
        const float cf = fabsf(qx[k] - tX) + fabsf(qy[k] - tY) + np_[k];
        double cur = ((double)cf - ui0) - vreg[k];
        if (usedMask & (1u << k)) cur = DINF;   // used => never wins strict <
        cv[k] = cur;
      }
      // within-lane tree min, left (smaller k) wins ties => first-occurrence
      double v0 = cv[0]; int k0 = 0;
      if (cv[1] < v0) { v0 = cv[1]; k0 = 1; }
      double v1 = cv[2]; int k1 = 2;
      if (cv[3] < v1) { v1 = cv[3]; k1 = 3; }
      double v2 = cv[4]; int k2 = 4;
      if (cv[5] < v2) { v2 = cv[5]; k2 = 5; }
      double v3 = cv[6]; int k3 = 6;
      if (cv[7] < v3) { v3 = cv[7]; k3 = 7; }
      if (v1 < v0) { v0 = v1; k0 = k1; }
      if (v3 < v2) { v2 = v3; k2 = k3; }
      double bval = v0; int bk = k0;
      if (v2 < v0) { bval = v2; bk = k2; }
      int bidx = 1 + tid + (bk << 8);

      // monotonic u64 bit-key of the per-lane winner (canonicalize -0 -> +0)
      bval += 0.0;
      const long long bb = __double_as_longlong(bval);
      const unsigned long long key = (unsigned long long)bb ^
          ((bb < 0) ? 0xFFFFFFFFFFFFFFFFull : 0x8000000000000000ull);
      const unsigned khi = (unsigned)(key >> 32);
      const unsigned klo = (unsigned)key;

      // wave argmin: DPP min on hi32, ballot for winner, exact ties slow path
      const unsigned minhi = wave_min_u32_dpp(khi);
      const unsigned long long mask = __ballot(khi == minhi);
      unsigned wklo; int widx;
      if (__popcll(mask) == 1) {
        const int wl = (int)__ffsll(mask) - 1;
        wklo = (unsigned)__builtin_amdgcn_readlane((int)klo, wl);
        widx = __builtin_amdgcn_readlane(bidx, wl);
      } else {
        wklo = 0xffffffffu; widx = 0x7fffffff;
        unsigned long long mm = mask;
        while (mm) {
          const int l = (int)__ffsll(mm) - 1; mm &= mm - 1;
          const unsigned lo2 = (unsigned)__builtin_amdgcn_readlane((int)klo, l);
          const int ix2 = __builtin_amdgcn_readlane(bidx, l);
          if (lo2 < wklo || (lo2 == wklo && ix2 < widx)) { wklo = lo2; widx = ix2; }
        }
      }
      const int par = s & 1;
      if (lane == 0) pk[par][wv] = make_uint4(minhi, wklo, (unsigned)widx, 0u);
      __syncthreads();            // the only per-step barrier

      // read the 4 packed candidates, then IMMEDIATELY prefetch their colDat
      const uint4 c0v = pk[par][0];
      const uint4 c1v = pk[par][1];
      const uint4 c2v = pk[par][2];
      const uint4 c3v = pk[par][3];
      const CD cd0 = colDat[(int)c0v.z];   // prefetch: latency overlaps combine
      const CD cd1 = colDat[(int)c1v.z];
      const CD cd2 = colDat[(int)c2v.z];
      const CD cd3 = colDat[(int)c3v.z];

      // cross-wave lexicographic reduce (identical order to R5)
      unsigned long long bkk = ((unsigned long long)c0v.x << 32) | c0v.y;
      int bj = (int)c0v.z, bw = 0;
      {
        const unsigned long long k2b = ((unsigned long long)c1v.x << 32) | c1v.y;
        const int j2 = (int)c1v.z;
        if (k2b < bkk || (k2b == bkk && j2 < bj)) { bkk = k2b; bj = j2; bw = 1; }
      }
      {
        const unsigned long long k2b = ((unsigned long long)c2v.x << 32) | c2v.y;
        const int j2 = (int)c2v.z;
        if (k2b < bkk || (k2b == bkk && j2 < bj)) { bkk = k2b; bj = j2; bw = 2; }
      }
      {
        const unsigned long long k2b = ((unsigned long long)c3v.x << 32) | c3v.y;
        const int j2 = (int)c3v.z;
        if (k2b < bkk || (k2b == bkk && j2 < bj)) { bkk = k2b; bj = j2; bw = 3; }
      }
      // invert bit-key -> delta (bitwise identical on every thread)
      const long long db = (long long)((bkk & 0x8000000000000000ull)
                                           ? (bkk ^ 0x8000000000000000ull) : ~bkk);
      const int j1 = bj;          // selected column, 1-based
      if (tid == 0) { visD[s] = D; visCol[s + 1] = (short)j1; }  // one exec region
      D += __longlong_as_double(db);
      if (tid == ((j1 - 1) & 255)) usedMask |= 1u << ((j1 - 1) >> 8);
      // select the winning wave's prefetched colDat
      CD cd = cd0;
      if (bw == 1) cd = cd1;
      if (bw == 2) cd = cd2;
      if (bw == 3) cd = cd3;
      ++s;
      if (cd.tx < 0.0f) { S = s; break; }   // free column => augmenting path done
      ui0 = cd.u; tX = cd.tx; tY = cd.ty;
    }

    // ---- epilogue: O(path) deferred updates (S <= 256 provable) ----
    __syncthreads();              // E0: in-search LDS traffic done
    const double Dfin = D;
    // snapshot pre-augment rows into registers
    const int rr0 = (tid < S) ? (int)p[(int)visCol[tid]] : 0;
    __syncthreads();              // E1
    if (tid < S) {
      const int cnew = (int)visCol[tid + 1];
      p[cnew] = (short)rr0;                       // augment
      const double unew = rowDat[rr0].u + (Dfin - visD[tid]);
      rowDat[rr0].u = unew;                       // u[row] += Dfin - visD[s]
      CD cd2; cd2.u = unew; cd2.tx = rowDat[rr0].tx; cd2.ty = rowDat[rr0].ty;
      colDat[cnew] = cd2;                         // refresh column cache (tx>=0)
    }
    // v updates for used cols visCol[1..S-1] (owner thread applies)
    for (int sv = 1; sv < S; ++sv) {
      const int qv = (int)visCol[sv] - 1;
      if ((qv & 255) == tid) vreg[qv >> 8] -= (Dfin - visD[sv]);
    }
    // next Bs barrier orders these writes before the next search's reads
  }
  __syncthreads();

  // ---- extract assignment, rank-sort (distinct values), write int32 ----
  for (int j = 1 + tid; j <= Q; j += NT) {
    const int pi = (int)p[j];
    if (pi > 0) ansArr[pi - 1] = j - 1;
  }
  __syncthreads();
  const int a = ansArr[tid];
  int rank = 0;
  for (int t2 = 0; t2 < T; ++t2) rank += (ansArr[t2] < a) ? 1 : 0;
  out[(size_t)b * T + rank] = a;                      // row_ind (sorted query idx)
  out[(size_t)B * T + (size_t)b * T + rank] = tid;    // col_ind (target idx)
}

extern "C" void kernel_launch(void* const* d_in, const int* in_sizes, int n_in,
                              void* d_out, int out_size, void* d_ws, size_t ws_size,
                              hipStream_t stream) {
  const float* outs = (const float*)d_in[0];   // (8, 2048, 3) fp32
  const float* tgts = (const float*)d_in[1];   // (8, 256, 3) fp32
  int* out = (int*)d_out;                      // row_ind (8,256) ++ col_ind (8,256)
  hungarian_r7<<<B, NT, 0, stream>>>(outs, tgts, out);
}

// Round 8
// 917.751 us; speedup vs baseline: 1.1873x; 1.0625x over previous
//
#include <hip/hip_runtime.h>

// GPUHungarianMatcher — exact replication of the reference's degenerate "_lsa"
// (minv reset every inner iteration => chain-Dijkstra). One block (4 waves)
// per batch. R8 = R7 step-loop + register-recorded path state (thread t
// records step t) => epilogue with no p-snapshot / no rowDat reads and only
// 2 barriers per row; within-lane argmin via fmin pass + equality select.
//
// Exactness invariants (validated by R2-R7 passing with absmax 0):
//  * cost fp32: fabsf(qx-tX)+fabsf(qy-tY)+np_, reduced fp64: ((double)cf-u)-v
//  * scans read only PRE-search u/v (path rows/cols distinct, p injective)
//  * argmin: minimum + smallest-j first occurrence (equality select descending
//    picks smallest k among exact equals, including +/-0) — same as tree
//  * u update: single add of prefix-difference on pre-search u (recU) —
//    identical value & rounding to R3-R7's validated rowDat read + add
//  * softmax bitwise-identical to the R2 tree (same thread mapping)
//  * free-flag: colDat[j].tx = -1.0f iff column j unmatched (real tx >= 0)

constexpr int B = 8;
constexpr int Q = 2048;        // columns (queries)
constexpr int T = 256;         // rows (targets)
constexpr int NT = 256;        // threads per block (4 waves)
constexpr int KPT = Q / NT;    // 8 columns per thread, j = 1 + tid + k*256
constexpr int NW = NT / 64;
constexpr double DINF = 1e300;

struct __align__(16) CD { double u; float tx, ty; };   // one ds_read_b128

__device__ __forceinline__ unsigned wave_min_u32_dpp(unsigned a) {
  // full-wave u32 min: row_shr 1,2,4,8 then row_bcast15, row_bcast31;
  // invalid source lanes keep old (bound_ctrl=false, masks 0xf) = identity.
  int v = (int)a, t;
  t = __builtin_amdgcn_update_dpp(v, v, 0x111, 0xf, 0xf, false);
  v = ((unsigned)t < (unsigned)v) ? t : v;
  t = __builtin_amdgcn_update_dpp(v, v, 0x112, 0xf, 0xf, false);
  v = ((unsigned)t < (unsigned)v) ? t : v;
  t = __builtin_amdgcn_update_dpp(v, v, 0x114, 0xf, 0xf, false);
  v = ((unsigned)t < (unsigned)v) ? t : v;
  t = __builtin_amdgcn_update_dpp(v, v, 0x118, 0xf, 0xf, false);
  v = ((unsigned)t < (unsigned)v) ? t : v;
  t = __builtin_amdgcn_update_dpp(v, v, 0x142, 0xf, 0xf, false);
  v = ((unsigned)t < (unsigned)v) ? t : v;
  t = __builtin_amdgcn_update_dpp(v, v, 0x143, 0xf, 0xf, false);
  v = ((unsigned)t < (unsigned)v) ? t : v;
  return (unsigned)__builtin_amdgcn_readlane(v, 63);   // lane 63 = global min
}

__launch_bounds__(NT, 1)
__global__ void hungarian_r8(const float* __restrict__ outs,
                             const float* __restrict__ tgts,
                             int* __restrict__ out) {
  const int b = blockIdx.x;
  const int tid = threadIdx.x;
  const int lane = tid & 63;
  const int wv = tid >> 6;

  __shared__ CD colDat[Q + 1];      // colDat[j] = {u[p[j]], tx[p[j]-1], ty[p[j]-1]}
                                    // tx = -1.0f marks a FREE column
  __shared__ CD rowDat[T + 1];      // rowDat[r] = {u[r], tx[r-1], ty[r-1]}
  __shared__ short p[Q + 1];        // p[j]: row matched to col j (1-based), 0 free
  __shared__ short visCol[T + 8];   // visit chain cols (for the v-update loop)
  __shared__ double visD[T + 8];    // delta prefix sums (for the v-update loop)
  __shared__ uint4 pk[2][NW];       // packed mailbox {khi, klo, idx, 0} (parity)
  __shared__ int ansArr[T];
  __shared__ double s_rv[NW];
  __shared__ float sh_f;

  const size_t qbase = (size_t)b * Q;
  const size_t tbase = (size_t)b * T;

  // ---- stage per-thread column data (fixed mapping j = 1 + tid + k*256) ----
  float xs[KPT], qx[KPT], qy[KPT];
#pragma unroll
  for (int k = 0; k < KPT; ++k) {
    const size_t o = (qbase + tid + k * NT) * 3;
    xs[k] = outs[o];
    qx[k] = outs[o + 1];
    qy[k] = outs[o + 2];
  }
  {
    const size_t o = (tbase + tid) * 3;   // T == NT: one target per thread
    rowDat[tid + 1].tx = tgts[o + 1];
    rowDat[tid + 1].ty = tgts[o + 2];
    rowDat[tid + 1].u = 0.0;
    if (tid == 0) { rowDat[0].tx = 0.f; rowDat[0].ty = 0.f; rowDat[0].u = 0.0; }
  }

  // ---- softmax over Q logits (bitwise-identical to the R2-passing tree) ----
  float lmax = xs[0];
#pragma unroll
  for (int k = 1; k < KPT; ++k) lmax = fmaxf(lmax, xs[k]);
  for (int off = 32; off > 0; off >>= 1) lmax = fmaxf(lmax, __shfl_down(lmax, off));
  if ((tid & 63) == 0) s_rv[tid >> 6] = (double)lmax;
  __syncthreads();
  if (tid == 0) {
    float m2 = (float)s_rv[0];
    for (int w = 1; w < NW; ++w) m2 = fmaxf(m2, (float)s_rv[w]);
    sh_f = m2;
  }
  __syncthreads();
  const float smax = sh_f;
  float ex[KPT];
  float lsum = 0.f;
#pragma unroll
  for (int k = 0; k < KPT; ++k) { ex[k] = expf(xs[k] - smax); lsum += ex[k]; }
  for (int off = 32; off > 0; off >>= 1) lsum += __shfl_down(lsum, off);
  if ((tid & 63) == 0) s_rv[tid >> 6] = (double)lsum;
  __syncthreads();
  if (tid == 0) {
    float s2 = 0.f;
    for (int w = 0; w < NW; ++w) s2 += (float)s_rv[w];
    sh_f = s2;
  }
  __syncthreads();
  const float ssum = sh_f;
  float np_[KPT];
#pragma unroll
  for (int k = 0; k < KPT; ++k) np_[k] = -(ex[k] / ssum);

  // ---- init state ----
  for (int j = tid; j <= Q; j += NT) {
    p[j] = 0;
    CD c0; c0.u = 0.0; c0.tx = -1.0f; c0.ty = 0.0f;   // all columns free
    colDat[j] = c0;
  }
  double vreg[KPT];   // v[j] for this thread's 8 columns
#pragma unroll
  for (int k = 0; k < KPT; ++k) vreg[k] = 0.0;
  __syncthreads();

  // ---- main loop over rows ----
  for (int i = 1; i <= T; ++i) {
    unsigned usedMask = 0;
    double D = 0.0;
    int i0 = i;
    double ui0 = rowDat[i].u;
    float tX = rowDat[i].tx, tY = rowDat[i].ty;
    int s = 0, S;
    int recRow = 0, recCol = 0;          // thread t records step t's state
    double recU = 0.0, recD = 0.0;
    float recTX = 0.f, recTY = 0.f;

    for (;;) {
      // record this step's pre-state on thread s (off the dependency spine)
      if (tid == s) { recRow = i0; recU = ui0; recTX = tX; recTY = tY; recD = D; }

      // scan my 8 unused columns: cur = ((double)cf - u[i0]) - v[j]
      double cv[KPT];
#pragma unroll
      for (int k = 0; k < KPT; ++k) {
        const float cf = fabsf(qx[k] - tX) + fabsf(qy[k] - tY) + np_[k];
        double cur = ((double)cf - ui0) - vreg[k];
        if (usedMask & (1u << k)) cur = DINF;   // used => never wins
        cv[k] = cur;
      }
      // within-lane argmin: fmin pass, then equality select (descending k =>
      // smallest k among exact equals = first occurrence; +/-0 both match)
      const double m01 = fmin(cv[0], cv[1]), m23 = fmin(cv[2], cv[3]);
      const double m45 = fmin(cv[4], cv[5]), m67 = fmin(cv[6], cv[7]);
      const double m03 = fmin(m01, m23), m47 = fmin(m45, m67);
      double bval = fmin(m03, m47);
      int bk = 7;
      if (cv[6] == bval) bk = 6;
      if (cv[5] == bval) bk = 5;
      if (cv[4] == bval) bk = 4;
      if (cv[3] == bval) bk = 3;
      if (cv[2] == bval) bk = 2;
      if (cv[1] == bval) bk = 1;
      if (cv[0] == bval) bk = 0;
      int bidx = 1 + tid + (bk << 8);

      // monotonic u64 bit-key of the per-lane winner (canonicalize -0 -> +0)
      bval += 0.0;
      const long long bb = __double_as_longlong(bval);
      const unsigned long long key = (unsigned long long)bb ^
          ((bb < 0) ? 0xFFFFFFFFFFFFFFFFull : 0x8000000000000000ull);
      const unsigned khi = (unsigned)(key >> 32);
      const unsigned klo = (unsigned)key;

      // wave argmin: DPP min on hi32, ballot for winner, exact ties slow path
      const unsigned minhi = wave_min_u32_dpp(khi);
      const unsigned long long mask = __ballot(khi == minhi);
      unsigned wklo; int widx;
      if (__popcll(mask) == 1) {
        const int wl = (int)__ffsll(mask) - 1;
        wklo = (unsigned)__builtin_amdgcn_readlane((int)klo, wl);
        widx = __builtin_amdgcn_readlane(bidx, wl);
      } else {
        wklo = 0xffffffffu; widx = 0x7fffffff;
        unsigned long long mm = mask;
        while (mm) {
          const int l = (int)__ffsll(mm) - 1; mm &= mm - 1;
          const unsigned lo2 = (unsigned)__builtin_amdgcn_readlane((int)klo, l);
          const int ix2 = __builtin_amdgcn_readlane(bidx, l);
          if (lo2 < wklo || (lo2 == wklo && ix2 < widx)) { wklo = lo2; widx = ix2; }
        }
      }
      const int par = s & 1;
      if (lane == 0) pk[par][wv] = make_uint4(minhi, wklo, (unsigned)widx, 0u);
      __syncthreads();            // the only per-step barrier

      // read the 4 packed candidates, then IMMEDIATELY prefetch their colDat
      const uint4 c0v = pk[par][0];
      const uint4 c1v = pk[par][1];
      const uint4 c2v = pk[par][2];
      const uint4 c3v = pk[par][3];
      const CD cd0 = colDat[(int)c0v.z];   // prefetch: latency overlaps combine
      const CD cd1 = colDat[(int)c1v.z];
      const CD cd2 = colDat[(int)c2v.z];
      const CD cd3 = colDat[(int)c3v.z];

      // cross-wave lexicographic reduce (identical order to R5-R7)
      unsigned long long bkk = ((unsigned long long)c0v.x << 32) | c0v.y;
      int bj = (int)c0v.z, bw = 0;
      {
        const unsigned long long k2b = ((unsigned long long)c1v.x << 32) | c1v.y;
        const int j2 = (int)c1v.z;
        if (k2b < bkk || (k2b == bkk && j2 < bj)) { bkk = k2b; bj = j2; bw = 1; }
      }
      {
        const unsigned long long k2b = ((unsigned long long)c2v.x << 32) | c2v.y;
        const int j2 = (int)c2v.z;
        if (k2b < bkk || (k2b == bkk && j2 < bj)) { bkk = k2b; bj = j2; bw = 2; }
      }
      {
        const unsigned long long k2b = ((unsigned long long)c3v.x << 32) | c3v.y;
        const int j2 = (int)c3v.z;
        if (k2b < bkk || (k2b == bkk && j2 < bj)) { bkk = k2b; bj = j2; bw = 3; }
      }
      // invert bit-key -> delta (bitwise identical on every thread)
      const long long db = (long long)((bkk & 0x8000000000000000ull)
                                           ? (bkk ^ 0x8000000000000000ull) : ~bkk);
      D += __longlong_as_double(db);
      const int j1 = bj;          // selected column, 1-based
      if (tid == ((j1 - 1) & 255)) usedMask |= 1u << ((j1 - 1) >> 8);
      if (tid == s) recCol = j1;
      const int pj1 = (int)p[j1];   // off-path: feeds only next step's recorder
      // select the winning wave's prefetched colDat
      CD cd = cd0;
      if (bw == 1) cd = cd1;
      if (bw == 2) cd = cd2;
      if (bw == 3) cd = cd3;
      ++s;
      if (cd.tx < 0.0f) { S = s; break; }   // free column => path complete
      ui0 = cd.u; tX = cd.tx; tY = cd.ty; i0 = pj1;
    }

    // ---- epilogue: O(path) deferred updates from recorded registers ----
    __syncthreads();              // E: all waves done stepping
    const double Dfin = D;
    if (tid < S) {
      visCol[tid + 1] = (short)recCol;            // for the v-update loop
      visD[tid] = recD;
      p[recCol] = (short)recRow;                  // augment (rows/cols distinct)
      const double unew = recU + (Dfin - recD);   // same single-add as R3-R7
      rowDat[recRow].u = unew;
      CD c2; c2.u = unew; c2.tx = recTX; c2.ty = recTY;
      colDat[recCol] = c2;                        // refresh cache (tx >= 0)
    }
    __syncthreads();              // F: epilogue writes visible
    // v updates for used cols visCol[1..S-1] (owner thread applies)
    for (int sv = 1; sv < S; ++sv) {
      const int qv = (int)visCol[sv] - 1;
      if ((qv & 255) == tid) vreg[qv >> 8] -= (Dfin - visD[sv]);
    }
    // next row's search reads (rowDat/colDat/p) ordered by F; visCol/visD
    // overwrites happen only after the next E barrier
  }
  __syncthreads();

  // ---- extract assignment, rank-sort (distinct values), write int32 ----
  for (int j = 1 + tid; j <= Q; j += NT) {
    const int pi = (int)p[j];
    if (pi > 0) ansArr[pi - 1] = j - 1;
  }
  __syncthreads();
  const int a = ansArr[tid];
  int rank = 0;
  for (int t2 = 0; t2 < T; ++t2) rank += (ansArr[t2] < a) ? 1 : 0;
  out[(size_t)b * T + rank] = a;                      // row_ind (sorted query idx)
  out[(size_t)B * T + (size_t)b * T + rank] = tid;    // col_ind (target idx)
}

extern "C" void kernel_launch(void* const* d_in, const int* in_sizes, int n_in,
                              void* d_out, int out_size, void* d_ws, size_t ws_size,
                              hipStream_t stream) {
  const float* outs = (const float*)d_in[0];   // (8, 2048, 3) fp32
  const float* tgts = (const float*)d_in[1];   // (8, 256, 3) fp32
  int* out = (int*)d_out;                      // row_ind (8,256) ++ col_ind (8,256)
  hungarian_r8<<<B, NT, 0, stream>>>(outs, tgts, out);
}

// Round 9
// 910.853 us; speedup vs baseline: 1.1963x; 1.0076x over previous
//
#include <hip/hip_runtime.h>

// GPUHungarianMatcher — exact replication of the reference's degenerate "_lsa"
// (minv reset every inner iteration => chain-Dijkstra). One block (4 waves)
// per batch. R9 = R8 + depth-reduced selects: (a) lane equality-select via
// parallel == compares -> bitmask -> ctz; (b) cross-wave combine as pairwise
// tournament with CD selection folded per level (depth 2 instead of 3+3).
//
// Exactness invariants (validated by R2-R8 passing with absmax 0):
//  * cost fp32: fabsf(qx-tX)+fabsf(qy-tY)+np_, reduced fp64: ((double)cf-u)-v
//  * scans read only PRE-search u/v (path rows/cols distinct, p injective)
//  * argmin: fmin + smallest-k among exact equals (ctz of ==-mask; +/-0 both
//    compare equal, same as the R8 chain) = np.argmin first occurrence
//  * pairwise tournament: left wins ties at every level => same winner as
//    R8's left-to-right scan (min + earliest index, keys lexicographic)
//  * u update: single add of prefix-difference on pre-search u (recU)
//  * softmax bitwise-identical to the R2 tree (same thread mapping)
//  * free-flag: colDat[j].tx = -1.0f iff column j unmatched (real tx >= 0)

constexpr int B = 8;
constexpr int Q = 2048;        // columns (queries)
constexpr int T = 256;         // rows (targets)
constexpr int NT = 256;        // threads per block (4 waves)
constexpr int KPT = Q / NT;    // 8 columns per thread, j = 1 + tid + k*256
constexpr int NW = NT / 64;
constexpr double DINF = 1e300;

struct __align__(16) CD { double u; float tx, ty; };   // one ds_read_b128

__device__ __forceinline__ unsigned wave_min_u32_dpp(unsigned a) {
  // full-wave u32 min: row_shr 1,2,4,8 then row_bcast15, row_bcast31;
  // invalid source lanes keep old (bound_ctrl=false, masks 0xf) = identity.
  int v = (int)a, t;
  t = __builtin_amdgcn_update_dpp(v, v, 0x111, 0xf, 0xf, false);
  v = ((unsigned)t < (unsigned)v) ? t : v;
  t = __builtin_amdgcn_update_dpp(v, v, 0x112, 0xf, 0xf, false);
  v = ((unsigned)t < (unsigned)v) ? t : v;
  t = __builtin_amdgcn_update_dpp(v, v, 0x114, 0xf, 0xf, false);
  v = ((unsigned)t < (unsigned)v) ? t : v;
  t = __builtin_amdgcn_update_dpp(v, v, 0x118, 0xf, 0xf, false);
  v = ((unsigned)t < (unsigned)v) ? t : v;
  t = __builtin_amdgcn_update_dpp(v, v, 0x142, 0xf, 0xf, false);
  v = ((unsigned)t < (unsigned)v) ? t : v;
  t = __builtin_amdgcn_update_dpp(v, v, 0x143, 0xf, 0xf, false);
  v = ((unsigned)t < (unsigned)v) ? t : v;
  return (unsigned)__builtin_amdgcn_readlane(v, 63);   // lane 63 = global min
}

__launch_bounds__(NT, 1)
__global__ void hungarian_r9(const float* __restrict__ outs,
                             const float* __restrict__ tgts,
                             int* __restrict__ out) {
  const int b = blockIdx.x;
  const int tid = threadIdx.x;
  const int lane = tid & 63;
  const int wv = tid >> 6;

  __shared__ CD colDat[Q + 1];      // colDat[j] = {u[p[j]], tx[p[j]-1], ty[p[j]-1]}
                                    // tx = -1.0f marks a FREE column
  __shared__ CD rowDat[T + 1];      // rowDat[r] = {u[r], tx[r-1], ty[r-1]}
  __shared__ short p[Q + 1];        // p[j]: row matched to col j (1-based), 0 free
  __shared__ short visCol[T + 8];   // visit chain cols (for the v-update loop)
  __shared__ double visD[T + 8];    // delta prefix sums (for the v-update loop)
  __shared__ uint4 pk[2][NW];       // packed mailbox {khi, klo, idx, 0} (parity)
  __shared__ int ansArr[T];
  __shared__ double s_rv[NW];
  __shared__ float sh_f;

  const size_t qbase = (size_t)b * Q;
  const size_t tbase = (size_t)b * T;

  // ---- stage per-thread column data (fixed mapping j = 1 + tid + k*256) ----
  float xs[KPT], qx[KPT], qy[KPT];
#pragma unroll
  for (int k = 0; k < KPT; ++k) {
    const size_t o = (qbase + tid + k * NT) * 3;
    xs[k] = outs[o];
    qx[k] = outs[o + 1];
    qy[k] = outs[o + 2];
  }
  {
    const size_t o = (tbase + tid) * 3;   // T == NT: one target per thread
    rowDat[tid + 1].tx = tgts[o + 1];
    rowDat[tid + 1].ty = tgts[o + 2];
    rowDat[tid + 1].u = 0.0;
    if (tid == 0) { rowDat[0].tx = 0.f; rowDat[0].ty = 0.f; rowDat[0].u = 0.0; }
  }

  // ---- softmax over Q logits (bitwise-identical to the R2-passing tree) ----
  float lmax = xs[0];
#pragma unroll
  for (int k = 1; k < KPT; ++k) lmax = fmaxf(lmax, xs[k]);
  for (int off = 32; off > 0; off >>= 1) lmax = fmaxf(lmax, __shfl_down(lmax, off));
  if ((tid & 63) == 0) s_rv[tid >> 6] = (double)lmax;
  __syncthreads();
  if (tid == 0) {
    float m2 = (float)s_rv[0];
    for (int w = 1; w < NW; ++w) m2 = fmaxf(m2, (float)s_rv[w]);
    sh_f = m2;
  }
  __syncthreads();
  const float smax = sh_f;
  float ex[KPT];
  float lsum = 0.f;
#pragma unroll
  for (int k = 0; k < KPT; ++k) { ex[k] = expf(xs[k] - smax); lsum += ex[k]; }
  for (int off = 32; off > 0; off >>= 1) lsum += __shfl_down(lsum, off);
  if ((tid & 63) == 0) s_rv[tid >> 6] = (double)lsum;
  __syncthreads();
  if (tid == 0) {
    float s2 = 0.f;
    for (int w = 0; w < NW; ++w) s2 += (float)s_rv[w];
    sh_f = s2;
  }
  __syncthreads();
  const float ssum = sh_f;
  float np_[KPT];
#pragma unroll
  for (int k = 0; k < KPT; ++k) np_[k] = -(ex[k] / ssum);

  // ---- init state ----
  for (int j = tid; j <= Q; j += NT) {
    p[j] = 0;
    CD c0; c0.u = 0.0; c0.tx = -1.0f; c0.ty = 0.0f;   // all columns free
    colDat[j] = c0;
  }
  double vreg[KPT];   // v[j] for this thread's 8 columns
#pragma unroll
  for (int k = 0; k < KPT; ++k) vreg[k] = 0.0;
  __syncthreads();

  // ---- main loop over rows ----
  for (int i = 1; i <= T; ++i) {
    unsigned usedMask = 0;
    double D = 0.0;
    int i0 = i;
    double ui0 = rowDat[i].u;
    float tX = rowDat[i].tx, tY = rowDat[i].ty;
    int s = 0, S;
    int recRow = 0, recCol = 0;          // thread t records step t's state
    double recU = 0.0, recD = 0.0;
    float recTX = 0.f, recTY = 0.f;

    for (;;) {
      // record this step's pre-state on thread s (off the dependency spine)
      if (tid == s) { recRow = i0; recU = ui0; recTX = tX; recTY = tY; recD = D; }

      // scan my 8 unused columns: cur = ((double)cf - u[i0]) - v[j]
      double cv[KPT];
#pragma unroll
      for (int k = 0; k < KPT; ++k) {
        const float cf = fabsf(qx[k] - tX) + fabsf(qy[k] - tY) + np_[k];
        double cur = ((double)cf - ui0) - vreg[k];
        if (usedMask & (1u << k)) cur = DINF;   // used => never wins
        cv[k] = cur;
      }
      // within-lane argmin: fmin tree for the value, then parallel ==-mask +
      // ctz => smallest k among exact equals (first occurrence; +/-0 match)
      const double m01 = fmin(cv[0], cv[1]), m23 = fmin(cv[2], cv[3]);
      const double m45 = fmin(cv[4], cv[5]), m67 = fmin(cv[6], cv[7]);
      const double m03 = fmin(m01, m23), m47 = fmin(m45, m67);
      double bval = fmin(m03, m47);
      unsigned emsk = 0;
#pragma unroll
      for (int k = 0; k < KPT; ++k) emsk |= (cv[k] == bval) ? (1u << k) : 0u;
      const int bk = (int)__builtin_ctz(emsk);   // emsk != 0 always
      int bidx = 1 + tid + (bk << 8);

      // monotonic u64 bit-key of the per-lane winner (canonicalize -0 -> +0)
      bval += 0.0;
      const long long bb = __double_as_longlong(bval);
      const unsigned long long key = (unsigned long long)bb ^
          ((bb < 0) ? 0xFFFFFFFFFFFFFFFFull : 0x8000000000000000ull);
      const unsigned khi = (unsigned)(key >> 32);
      const unsigned klo = (unsigned)key;

      // wave argmin: DPP min on hi32, ballot for winner, exact ties slow path
      const unsigned minhi = wave_min_u32_dpp(khi);
      const unsigned long long mask = __ballot(khi == minhi);
      unsigned wklo; int widx;
      if (__popcll(mask) == 1) {
        const int wl = (int)__ffsll(mask) - 1;
        wklo = (unsigned)__builtin_amdgcn_readlane((int)klo, wl);
        widx = __builtin_amdgcn_readlane(bidx, wl);
      } else {
        wklo = 0xffffffffu; widx = 0x7fffffff;
        unsigned long long mm = mask;
        while (mm) {
          const int l = (int)__ffsll(mm) - 1; mm &= mm - 1;
          const unsigned lo2 = (unsigned)__builtin_amdgcn_readlane((int)klo, l);
          const int ix2 = __builtin_amdgcn_readlane(bidx, l);
          if (lo2 < wklo || (lo2 == wklo && ix2 < widx)) { wklo = lo2; widx = ix2; }
        }
      }
      const int par = s & 1;
      if (lane == 0) pk[par][wv] = make_uint4(minhi, wklo, (unsigned)widx, 0u);
      __syncthreads();            // the only per-step barrier

      // read the 4 packed candidates, then IMMEDIATELY prefetch their colDat
      const uint4 c0v = pk[par][0];
      const uint4 c1v = pk[par][1];
      const uint4 c2v = pk[par][2];
      const uint4 c3v = pk[par][3];
      const CD cd0 = colDat[(int)c0v.z];   // prefetch: latency overlaps combine
      const CD cd1 = colDat[(int)c1v.z];
      const CD cd2 = colDat[(int)c2v.z];
      const CD cd3 = colDat[(int)c3v.z];

      // cross-wave pairwise tournament (left wins ties at every level ==
      // same winner as the left-to-right scan of R5-R8)
      const unsigned long long k0b = ((unsigned long long)c0v.x << 32) | c0v.y;
      const unsigned long long k1b = ((unsigned long long)c1v.x << 32) | c1v.y;
      const unsigned long long k2b = ((unsigned long long)c2v.x << 32) | c2v.y;
      const unsigned long long k3b = ((unsigned long long)c3v.x << 32) | c3v.y;
      const int j0b = (int)c0v.z, j1bb = (int)c1v.z;
      const int j2b = (int)c2v.z, j3b = (int)c3v.z;
      // level 1 (pairs 01 and 23, independent)
      const bool w01 = (k1b < k0b) || (k1b == k0b && j1bb < j0b);
      const unsigned long long k01 = w01 ? k1b : k0b;
      const int j01 = w01 ? j1bb : j0b;
      const bool w23 = (k3b < k2b) || (k3b == k2b && j3b < j2b);
      const unsigned long long k23 = w23 ? k3b : k2b;
      const int j23 = w23 ? j3b : j2b;
      // level 2 (final)
      const bool wf = (k23 < k01) || (k23 == k01 && j23 < j01);
      const unsigned long long bkk = wf ? k23 : k01;
      const int j1 = wf ? j23 : j01;          // selected column, 1-based
      // CD selection folded along the same tournament (depth 2)
      CD cdA; cdA.u = w01 ? cd1.u : cd0.u;
      cdA.tx = w01 ? cd1.tx : cd0.tx; cdA.ty = w01 ? cd1.ty : cd0.ty;
      CD cdB; cdB.u = w23 ? cd3.u : cd2.u;
      cdB.tx = w23 ? cd3.tx : cd2.tx; cdB.ty = w23 ? cd3.ty : cd2.ty;
      CD cd; cd.u = wf ? cdB.u : cdA.u;
      cd.tx = wf ? cdB.tx : cdA.tx; cd.ty = wf ? cdB.ty : cdA.ty;

      // invert bit-key -> delta (bitwise identical on every thread)
      const long long db = (long long)((bkk & 0x8000000000000000ull)
                                           ? (bkk ^ 0x8000000000000000ull) : ~bkk);
      D += __longlong_as_double(db);
      if (tid == ((j1 - 1) & 255)) usedMask |= 1u << ((j1 - 1) >> 8);
      if (tid == s) recCol = j1;
      const int pj1 = (int)p[j1];   // off-path: feeds only next step's recorder
      ++s;
      if (cd.tx < 0.0f) { S = s; break; }   // free column => path complete
      ui0 = cd.u; tX = cd.tx; tY = cd.ty; i0 = pj1;
    }

    // ---- epilogue: O(path) deferred updates from recorded registers ----
    __syncthreads();              // E: all waves done stepping
    const double Dfin = D;
    if (tid < S) {
      visCol[tid + 1] = (short)recCol;            // for the v-update loop
      visD[tid] = recD;
      p[recCol] = (short)recRow;                  // augment (rows/cols distinct)
      const double unew = recU + (Dfin - recD);   // same single-add as R3-R8
      rowDat[recRow].u = unew;
      CD c2; c2.u = unew; c2.tx = recTX; c2.ty = recTY;
      colDat[recCol] = c2;                        // refresh cache (tx >= 0)
    }
    __syncthreads();              // F: epilogue writes visible
    // v updates for used cols visCol[1..S-1] (owner thread applies)
    for (int sv = 1; sv < S; ++sv) {
      const int qv = (int)visCol[sv] - 1;
      if ((qv & 255) == tid) vreg[qv >> 8] -= (Dfin - visD[sv]);
    }
    // next row's search reads (rowDat/colDat/p) ordered by F; visCol/visD
    // overwrites happen only after the next E barrier
  }
  __syncthreads();

  // ---- extract assignment, rank-sort (distinct values), write int32 ----
  for (int j = 1 + tid; j <= Q; j += NT) {
    const int pi = (int)p[j];
    if (pi > 0) ansArr[pi - 1] = j - 1;
  }
  __syncthreads();
  const int a = ansArr[tid];
  int rank = 0;
  for (int t2 = 0; t2 < T; ++t2) rank += (ansArr[t2] < a) ? 1 : 0;
  out[(size_t)b * T + rank] = a;                      // row_ind (sorted query idx)
  out[(size_t)B * T + (size_t)b * T + rank] = tid;    // col_ind (target idx)
}

extern "C" void kernel_launch(void* const* d_in, const int* in_sizes, int n_in,
                              void* d_out, int out_size, void* d_ws, size_t ws_size,
                              hipStream_t stream) {
  const float* outs = (const float*)d_in[0];   // (8, 2048, 3) fp32
  const float* tgts = (const float*)d_in[1];   // (8, 256, 3) fp32
  int* out = (int*)d_out;                      // row_ind (8,256) ++ col_ind (8,256)
  hungarian_r9<<<B, NT, 0, stream>>>(outs, tgts, out);
}